// Round 8
// baseline (1244.889 us; speedup 1.0000x reference)
//
#include <hip/hip_runtime.h>

typedef _Float16 f16;
typedef _Float16 f16x4 __attribute__((ext_vector_type(4)));
typedef _Float16 f16x8 __attribute__((ext_vector_type(8)));
typedef float f32x4 __attribute__((ext_vector_type(4)));

#define MFMA16(a, b, c) __builtin_amdgcn_mfma_f32_16x16x32_f16((a), (b), (c), 0, 0, 0)

// ---- Tsit5 coefficients (fp32) ----
#define A21f 0.161f
#define A31f (-0.008480655492356989f)
#define A32f 0.335480655492357f
#define A41f 2.8971530571054935f
#define A42f (-6.359448489975075f)
#define A43f 4.3622954328695815f
#define A51f 5.325864828439257f
#define A52f (-11.748883564062828f)
#define A53f 7.4955393428898365f
#define A54f (-0.09249506636175525f)
#define A61f 5.86145544294642f
#define A62f (-12.92096931784711f)
#define A63f 8.159367898576159f
#define A64f (-0.071584973281401f)
#define A65f (-0.028269050394068383f)
#define B1f 0.09646076681806523f
#define B2f 0.01f
#define B3f 0.4798896504144996f
#define B4f 1.379008574103742f
#define B5f (-3.290069515436081f)
#define B6f 2.324710524099774f
#define C2f 0.161f
#define C3f 0.327f
#define C4f 0.9f
#define C5f 0.9800255409045097f
#define C6f 1.0f

// ---- LDS layout: FRAGMENT-MAJOR activation tiles ----
// addr(row, k) = base + ((k>>3)*16 + row)*16 + (k&7)*2
//   reads : lane l does ds_read_b128 at base + kt*1024 + l*16 (contiguous/wave)
//   writes: swapped-operand MFMA -> lane holds 4 consecutive k for batch lr
//           -> one ds_write_b64, even bank spread
// Y: 16x128k (4KB) | Z1/Z2: 16x256k (8KB; Z1 k>=128 = Static|0)
// X: 16x32k (1KB) | TS: 16x64 f32 (4KB)
// WH: 128out x 128k frag-major: addr(c,k)=((k>>3)*128+c)*16+(k&7)*2 (32KB)
#define LDS_Y   0
#define LDS_Z1  4096
#define LDS_Z2  12288
#define LDS_X   20480
#define LDS_TS  21504
#define LDS_WH  25600
#define LDS_TOT 58368

// branch-free fast activations (v_exp + v_rcp)
__device__ __forceinline__ float tanh_fast(float x) {
  return 2.0f * __builtin_amdgcn_rcpf(1.0f + __expf(-2.0f * x)) - 1.0f;
}
__device__ __forceinline__ float siluf(float x) {
  return x * __builtin_amdgcn_rcpf(1.0f + __expf(-x));
}

__global__ __launch_bounds__(512, 2)
void ode_rnn_kernel(const float* __restrict__ ts, const float* __restrict__ Xg,
                    const float* __restrict__ Sg,
                    const float* __restrict__ w0g, const float* __restrict__ b0g,
                    const float* __restrict__ w1g, const float* __restrict__ b1g,
                    const float* __restrict__ w2g, const float* __restrict__ b2g,
                    const float* __restrict__ scaleg,
                    const float* __restrict__ whg, const float* __restrict__ wxg,
                    const float* __restrict__ bxg,
                    const float* __restrict__ injwg, const float* __restrict__ injbg,
                    const float* __restrict__ ow0g, const float* __restrict__ ob0g,
                    const float* __restrict__ ow1g, const float* __restrict__ ob1g,
                    const float* __restrict__ ow2g, const float* __restrict__ ob2g,
                    float* __restrict__ outg) {
  const int t  = threadIdx.x;
  const int w  = t >> 6;       // wave 0..7
  const int l  = t & 63;       // lane
  const int lr = l & 15;       // batch row owned by this lane
  const int lg = l >> 4;       // 0..3
  const int rb = blockIdx.x * 16;
  const int c1 = w * 32;       // out-chan base, 256-wide stages
  const int c3 = w * 16;       // out-chan base, 128-wide stages

  __shared__ __align__(16) unsigned char lds[LDS_TOT];

  const int ard  = l * 16;                                   // frag read base (+kt*1024)
  const int whrd = LDS_WH + lg * 2048 + w * 256 + lr * 16;   // WH A-frag base (+kt*8192)
  const int awb  = (lg >> 1) * 256 + lr * 16 + (lg & 1) * 8; // b64 write base

  // ---------------- one-time staging into LDS ----------------
  for (int e = t; e < 16 * 64; e += 512) {
    *(float*)(lds + LDS_TS + e * 4) = ts[(size_t)(rb + (e >> 6)) * 64 + (e & 63)];
  }
  for (int e = t; e < 128 * 128; e += 512) {
    int c = e >> 7, kk = e & 127;
    *(f16*)(lds + LDS_WH + ((kk >> 3) * 128 + c) * 16 + (kk & 7) * 2) = (f16)whg[e];
  }
  {
    int r = t >> 5, d = t & 31;
    *(f16*)(lds + LDS_X + (d >> 3) * 256 + r * 16 + (d & 7) * 2) =
        (f16)Xg[(size_t)(rb + r) * 2048 + d];
  }
  if (t < 256) {
    int r = t >> 4, c = t & 15;
    *(f16*)(lds + LDS_Z1 + 4096 + (c >> 3) * 256 + r * 16 + (c & 7) * 2) =
        (f16)Sg[(size_t)(rb + r) * 16 + c];
    *(f16*)(lds + LDS_Z1 + 4608 + (c >> 3) * 256 + r * 16 + (c & 7) * 2) = (f16)0.0f;
  }

  // ---------------- per-channel constants (lane holds chans base+lg*4+r) ----------------
  f32x4 b0q[2], b1q[2];
  float w0c0[2][4];
  #pragma unroll
  for (int nt = 0; nt < 2; ++nt) {
    b0q[nt] = *(const f32x4*)(b0g + c1 + nt * 16 + lg * 4);
    b1q[nt] = *(const f32x4*)(b1g + c1 + nt * 16 + lg * 4);
    #pragma unroll
    for (int r = 0; r < 4; ++r)
      w0c0[nt][r] = w0g[(size_t)(c1 + nt * 16 + lg * 4 + r) * 129];
  }
  const f32x4 b2q = *(const f32x4*)(b2g + c3 + lg * 4);
  const f32x4 bxq = *(const f32x4*)(bxg + c3 + lg * 4);
  const float scalev = scaleg[0];

  // ---------------- register-resident weight fragments (f16, A-operand) ----------------
  auto ldfrag = [](const float* p) {
    f16x8 v;
    #pragma unroll
    for (int j = 0; j < 8; ++j) v[j] = (f16)p[j];
    return v;
  };

  f16x8 W0f[4][2];
  #pragma unroll
  for (int kt = 0; kt < 4; ++kt)
    #pragma unroll
    for (int nt = 0; nt < 2; ++nt)
      W0f[kt][nt] = ldfrag(w0g + (size_t)(c1 + nt * 16 + lr) * 129 + 1 + kt * 32 + lg * 8);

  f16x8 W1f[8][2];
  #pragma unroll
  for (int kt = 0; kt < 8; ++kt)
    #pragma unroll
    for (int nt = 0; nt < 2; ++nt)
      W1f[kt][nt] = ldfrag(w1g + (size_t)(c1 + nt * 16 + lr) * 256 + kt * 32 + lg * 8);

  f16x8 W2f[8];
  #pragma unroll
  for (int kt = 0; kt < 8; ++kt)
    W2f[kt] = ldfrag(w2g + (size_t)(c3 + lr) * 256 + kt * 32 + lg * 8);

  f16x8 WXf = ldfrag(wxg + (size_t)(c3 + lr) * 32 + lg * 8);

  __syncthreads();  // staging complete

  // ---------------- state ----------------
  float y[4];        // h[batch=lr][chan=c3+lg*4+r], fp32
  float tpv, dvv, dsv;

  auto writeY = [&](const float* yv) {
    f16x4 p;
    #pragma unroll
    for (int r = 0; r < 4; ++r) p[r] = (f16)yv[r];
    *(f16x4*)(lds + LDS_Y + w * 512 + awb) = p;
  };

  // ---------------- init: h0 = tanh(X0 @ wx.T + bx), then inj ----------------
  {
    f16x8 xa = *(const f16x8*)(lds + LDS_X + ard);
    f32x4 acc = bxq;                      // bias-init accumulator
    acc = MFMA16(WXf, xa, acc);
    f16x4 p;
    #pragma unroll
    for (int r = 0; r < 4; ++r) p[r] = (f16)tanh_fast(acc[r]);
    *(f16x4*)(lds + LDS_Z1 + w * 512 + awb) = p;   // h0 -> Z1 k=0..127
  }
  __syncthreads();
  {
    f16x8 af[5];
    #pragma unroll
    for (int kt = 0; kt < 5; ++kt) af[kt] = *(const f16x8*)(lds + LDS_Z1 + ard + kt * 1024);
    f32x4 acc = *(const f32x4*)(injbg + c3 + lg * 4);   // bias-init
    #pragma unroll
    for (int kt = 0; kt < 5; ++kt) {
      f16x8 bf;
      #pragma unroll
      for (int j = 0; j < 8; ++j) {
        int k = kt * 32 + lg * 8 + j;
        bf[j] = (k < 144) ? (f16)injwg[(size_t)(c3 + lr) * 144 + k] : (f16)0.0f;
      }
      acc = MFMA16(bf, af[kt], acc);
    }
    #pragma unroll
    for (int r = 0; r < 4; ++r) y[r] = tanh_fast(acc[r]);
  }
  writeY(y);
  __syncthreads();

  // ---------------- f(t,y): 3 MFMA stages, bias-init accumulators ----------------
  // ko = tanh(...)  (ode_scale folded into the combination coefficients)
  auto feval = [&](float sc, float* ko) {
    f16x8 af[8];
    // stage1: K=128 from Y, 256 chans, + t*w0[:,0], silu -> Z1
    #pragma unroll
    for (int kt = 0; kt < 4; ++kt) af[kt] = *(const f16x8*)(lds + LDS_Y + ard + kt * 1024);
    f32x4 a1[2], a1b[2] = {};
    a1[0] = b0q[0]; a1[1] = b0q[1];
    __builtin_amdgcn_s_setprio(1);
    #pragma unroll
    for (int kt = 0; kt < 2; ++kt)
      #pragma unroll
      for (int nt = 0; nt < 2; ++nt) {
        a1[nt]  = MFMA16(W0f[kt][nt],     af[kt],     a1[nt]);
        a1b[nt] = MFMA16(W0f[kt + 2][nt], af[kt + 2], a1b[nt]);
      }
    __builtin_amdgcn_s_setprio(0);
    const float tr = tpv + sc * dvv;
    #pragma unroll
    for (int nt = 0; nt < 2; ++nt) {
      f16x4 p;
      #pragma unroll
      for (int r = 0; r < 4; ++r)
        p[r] = (f16)siluf(a1[nt][r] + a1b[nt][r] + tr * w0c0[nt][r]);
      *(f16x4*)(lds + LDS_Z1 + w * 1024 + nt * 512 + awb) = p;
    }
    __syncthreads();
    // stage2: K=256 from Z1, 256 chans, silu -> Z2
    #pragma unroll
    for (int kt = 0; kt < 8; ++kt) af[kt] = *(const f16x8*)(lds + LDS_Z1 + ard + kt * 1024);
    f32x4 a2[2], a2b[2] = {};
    a2[0] = b1q[0]; a2[1] = b1q[1];
    __builtin_amdgcn_s_setprio(1);
    #pragma unroll
    for (int kt = 0; kt < 4; ++kt)
      #pragma unroll
      for (int nt = 0; nt < 2; ++nt) {
        a2[nt]  = MFMA16(W1f[kt][nt],     af[kt],     a2[nt]);
        a2b[nt] = MFMA16(W1f[kt + 4][nt], af[kt + 4], a2b[nt]);
      }
    __builtin_amdgcn_s_setprio(0);
    #pragma unroll
    for (int nt = 0; nt < 2; ++nt) {
      f16x4 p;
      #pragma unroll
      for (int r = 0; r < 4; ++r)
        p[r] = (f16)siluf(a2[nt][r] + a2b[nt][r]);
      *(f16x4*)(lds + LDS_Z2 + w * 1024 + nt * 512 + awb) = p;
    }
    __syncthreads();
    // stage3: K=256 from Z2, 128 chans, tanh -> k (registers, 4 chains)
    #pragma unroll
    for (int kt = 0; kt < 8; ++kt) af[kt] = *(const f16x8*)(lds + LDS_Z2 + ard + kt * 1024);
    f32x4 a3 = b2q, a3b = {}, a3c = {}, a3d = {};
    __builtin_amdgcn_s_setprio(1);
    #pragma unroll
    for (int kt = 0; kt < 2; ++kt) {
      a3  = MFMA16(W2f[kt],     af[kt],     a3);
      a3b = MFMA16(W2f[kt + 2], af[kt + 2], a3b);
      a3c = MFMA16(W2f[kt + 4], af[kt + 4], a3c);
      a3d = MFMA16(W2f[kt + 6], af[kt + 6], a3d);
    }
    __builtin_amdgcn_s_setprio(0);
    #pragma unroll
    for (int r = 0; r < 4; ++r)
      ko[r] = tanh_fast(((a3[r] + a3b[r]) + (a3c[r] + a3d[r])));
  };

  // ---------------- main time loop ----------------
  #pragma unroll 1
  for (int n = 0; n < 63; ++n) {
    {
      float tp = *(const float*)(lds + LDS_TS + (lr * 64 + n) * 4);
      float tn = *(const float*)(lds + LDS_TS + (lr * 64 + n + 1) * 4);
      tpv = tp;
      dvv = (tn - tp) * 0.5f;
      dsv = dvv * scalev;
    }
    // combination coefficients for this step (dsv constant across both substeps)
    const float e21 = dsv * A21f;
    const float e31 = dsv * A31f, e32 = dsv * A32f;
    const float e41 = dsv * A41f, e42 = dsv * A42f, e43 = dsv * A43f;
    const float e51 = dsv * A51f, e52 = dsv * A52f, e53 = dsv * A53f, e54 = dsv * A54f;
    const float e61 = dsv * A61f, e62 = dsv * A62f, e63 = dsv * A63f, e64 = dsv * A64f, e65 = dsv * A65f;
    const float eB1 = dsv * B1f, eB2 = dsv * B2f, eB3 = dsv * B3f,
                eB4 = dsv * B4f, eB5 = dsv * B5f, eB6 = dsv * B6f;

    // stage x = X[:, n+1] for this step's RNN (consumed after many barriers)
    {
      int r = t >> 5, d = t & 31;
      *(f16*)(lds + LDS_X + (d >> 3) * 256 + r * 16 + (d & 7) * 2) =
          (f16)Xg[(size_t)(rb + r) * 2048 + (size_t)(n + 1) * 32 + d];
    }

    #pragma unroll 1
    for (int s = 0; s < 2; ++s) {
      float kv[4], yt[4], p3[4], p4[4], p5[4], p6[4], pB[4];
      float sf = (float)s;

      feval(sf, kv);                       // k1
      #pragma unroll
      for (int i = 0; i < 4; ++i) yt[i] = fmaf(e21, kv[i], y[i]);
      writeY(yt);
      #pragma unroll
      for (int i = 0; i < 4; ++i) {        // future-stage partials (off critical path)
        p3[i] = fmaf(e31, kv[i], y[i]);
        p4[i] = fmaf(e41, kv[i], y[i]);
        p5[i] = fmaf(e51, kv[i], y[i]);
        p6[i] = fmaf(e61, kv[i], y[i]);
        pB[i] = fmaf(eB1, kv[i], y[i]);
      }
      __syncthreads();

      feval(sf + C2f, kv);                 // k2
      #pragma unroll
      for (int i = 0; i < 4; ++i) yt[i] = fmaf(e32, kv[i], p3[i]);
      writeY(yt);
      #pragma unroll
      for (int i = 0; i < 4; ++i) {
        p4[i] = fmaf(e42, kv[i], p4[i]);
        p5[i] = fmaf(e52, kv[i], p5[i]);
        p6[i] = fmaf(e62, kv[i], p6[i]);
        pB[i] = fmaf(eB2, kv[i], pB[i]);
      }
      __syncthreads();

      feval(sf + C3f, kv);                 // k3
      #pragma unroll
      for (int i = 0; i < 4; ++i) yt[i] = fmaf(e43, kv[i], p4[i]);
      writeY(yt);
      #pragma unroll
      for (int i = 0; i < 4; ++i) {
        p5[i] = fmaf(e53, kv[i], p5[i]);
        p6[i] = fmaf(e63, kv[i], p6[i]);
        pB[i] = fmaf(eB3, kv[i], pB[i]);
      }
      __syncthreads();

      feval(sf + C4f, kv);                 // k4
      #pragma unroll
      for (int i = 0; i < 4; ++i) yt[i] = fmaf(e54, kv[i], p5[i]);
      writeY(yt);
      #pragma unroll
      for (int i = 0; i < 4; ++i) {
        p6[i] = fmaf(e64, kv[i], p6[i]);
        pB[i] = fmaf(eB4, kv[i], pB[i]);
      }
      __syncthreads();

      feval(sf + C5f, kv);                 // k5
      #pragma unroll
      for (int i = 0; i < 4; ++i) yt[i] = fmaf(e65, kv[i], p6[i]);
      writeY(yt);
      #pragma unroll
      for (int i = 0; i < 4; ++i) pB[i] = fmaf(eB5, kv[i], pB[i]);
      __syncthreads();

      feval(sf + C6f, kv);                 // k6
      #pragma unroll
      for (int i = 0; i < 4; ++i) y[i] = fmaf(eB6, kv[i], pB[i]);
      writeY(y);
      __syncthreads();
    }

    // RNN: h = tanh(hp@wh.T + x@wx.T + bx); wh A-frags from LDS, wx from regs
    {
      f16x8 ha[4];
      #pragma unroll
      for (int kt = 0; kt < 4; ++kt) ha[kt] = *(const f16x8*)(lds + LDS_Y + ard + kt * 1024);
      f16x8 xa = *(const f16x8*)(lds + LDS_X + ard);
      f32x4 acc = bxq, accb = {};          // bias-init
      __builtin_amdgcn_s_setprio(1);
      #pragma unroll
      for (int kt = 0; kt < 2; ++kt) {
        f16x8 bf  = *(const f16x8*)(lds + whrd + kt * 8192);
        f16x8 bf2 = *(const f16x8*)(lds + whrd + (kt + 2) * 8192);
        acc  = MFMA16(bf,  ha[kt],     acc);
        accb = MFMA16(bf2, ha[kt + 2], accb);
      }
      acc = MFMA16(WXf, xa, acc);
      __builtin_amdgcn_s_setprio(0);
      #pragma unroll
      for (int r = 0; r < 4; ++r) y[r] = tanh_fast(acc[r] + accb[r]);
      writeY(y);
      __syncthreads();
    }
  }

  // ---------------- output head ----------------
  auto ldfrag2 = [](const float* p) {
    f16x8 v;
    #pragma unroll
    for (int j = 0; j < 8; ++j) v[j] = (f16)p[j];
    return v;
  };
  // H1: z = tanh(hN @ out_w0.T + out_b0)   K=128 -> 256 chans
  {
    f16x8 ha[4];
    #pragma unroll
    for (int kt = 0; kt < 4; ++kt) ha[kt] = *(const f16x8*)(lds + LDS_Y + ard + kt * 1024);
    f32x4 acc[2];
    acc[0] = *(const f32x4*)(ob0g + c1 + lg * 4);
    acc[1] = *(const f32x4*)(ob0g + c1 + 16 + lg * 4);
    #pragma unroll
    for (int kt = 0; kt < 4; ++kt)
      #pragma unroll
      for (int nt = 0; nt < 2; ++nt) {
        f16x8 bf = ldfrag2(ow0g + (size_t)(c1 + nt * 16 + lr) * 128 + kt * 32 + lg * 8);
        acc[nt] = MFMA16(bf, ha[kt], acc[nt]);
      }
    #pragma unroll
    for (int nt = 0; nt < 2; ++nt) {
      f16x4 p;
      #pragma unroll
      for (int r = 0; r < 4; ++r) p[r] = (f16)tanh_fast(acc[nt][r]);
      *(f16x4*)(lds + LDS_Z1 + w * 1024 + nt * 512 + awb) = p;
    }
  }
  __syncthreads();
  // H2: z = tanh(z @ out_w1.T + out_b1)   K=256 -> 256 chans
  {
    f16x8 za[8];
    #pragma unroll
    for (int kt = 0; kt < 8; ++kt) za[kt] = *(const f16x8*)(lds + LDS_Z1 + ard + kt * 1024);
    f32x4 acc[2];
    acc[0] = *(const f32x4*)(ob1g + c1 + lg * 4);
    acc[1] = *(const f32x4*)(ob1g + c1 + 16 + lg * 4);
    #pragma unroll
    for (int kt = 0; kt < 8; ++kt)
      #pragma unroll
      for (int nt = 0; nt < 2; ++nt) {
        f16x8 bf = ldfrag2(ow1g + (size_t)(c1 + nt * 16 + lr) * 256 + kt * 32 + lg * 8);
        acc[nt] = MFMA16(bf, za[kt], acc[nt]);
      }
    #pragma unroll
    for (int nt = 0; nt < 2; ++nt) {
      f16x4 p;
      #pragma unroll
      for (int r = 0; r < 4; ++r) p[r] = (f16)tanh_fast(acc[nt][r]);
      *(f16x4*)(lds + LDS_Z2 + w * 1024 + nt * 512 + awb) = p;
    }
  }
  __syncthreads();
  // H3: out = z @ out_w2.T + out_b2   K=256 -> 16 chans (wave 0 only)
  if (w == 0) {
    f16x8 za[8];
    #pragma unroll
    for (int kt = 0; kt < 8; ++kt) za[kt] = *(const f16x8*)(lds + LDS_Z2 + ard + kt * 1024);
    f32x4 acc = *(const f32x4*)(ob2g + lg * 4);
    #pragma unroll
    for (int kt = 0; kt < 8; ++kt) {
      f16x8 bf = ldfrag2(ow2g + (size_t)lr * 256 + kt * 32 + lg * 8);
      acc = MFMA16(bf, za[kt], acc);
    }
    *(f32x4*)(outg + (size_t)(rb + lr) * 16 + lg * 4) = acc;
  }
}

extern "C" void kernel_launch(void* const* d_in, const int* in_sizes, int n_in,
                              void* d_out, int out_size, void* d_ws, size_t ws_size,
                              hipStream_t stream) {
  (void)in_sizes; (void)n_in; (void)d_ws; (void)ws_size; (void)out_size;
  ode_rnn_kernel<<<dim3(8), dim3(512), 0, stream>>>(
      (const float*)d_in[0],  (const float*)d_in[1],  (const float*)d_in[2],
      (const float*)d_in[3],  (const float*)d_in[4],  (const float*)d_in[5],
      (const float*)d_in[6],  (const float*)d_in[7],  (const float*)d_in[8],
      (const float*)d_in[9],  (const float*)d_in[10], (const float*)d_in[11],
      (const float*)d_in[12], (const float*)d_in[13], (const float*)d_in[14],
      (const float*)d_in[15], (const float*)d_in[16], (const float*)d_in[17],
      (const float*)d_in[18], (const float*)d_in[19], (const float*)d_in[20],
      (float*)d_out);
}

// Round 9
// 1159.357 us; speedup vs baseline: 1.0738x; 1.0738x over previous
//
#include <hip/hip_runtime.h>

typedef _Float16 f16;
typedef _Float16 f16x4 __attribute__((ext_vector_type(4)));
typedef _Float16 f16x8 __attribute__((ext_vector_type(8)));
typedef float f32x4 __attribute__((ext_vector_type(4)));

#define MFMA16(a, b, c) __builtin_amdgcn_mfma_f32_16x16x32_f16((a), (b), (c), 0, 0, 0)

// ---- Tsit5 coefficients (fp32) ----
#define A21f 0.161f
#define A31f (-0.008480655492356989f)
#define A32f 0.335480655492357f
#define A41f 2.8971530571054935f
#define A42f (-6.359448489975075f)
#define A43f 4.3622954328695815f
#define A51f 5.325864828439257f
#define A52f (-11.748883564062828f)
#define A53f 7.4955393428898365f
#define A54f (-0.09249506636175525f)
#define A61f 5.86145544294642f
#define A62f (-12.92096931784711f)
#define A63f 8.159367898576159f
#define A64f (-0.071584973281401f)
#define A65f (-0.028269050394068383f)
#define B1f 0.09646076681806523f
#define B2f 0.01f
#define B3f 0.4798896504144996f
#define B4f 1.379008574103742f
#define B5f (-3.290069515436081f)
#define B6f 2.324710524099774f
#define C2f 0.161f
#define C3f 0.327f
#define C4f 0.9f
#define C5f 0.9800255409045097f
#define C6f 1.0f

// ---- LDS layout: FRAGMENT-MAJOR activation tiles ----
// addr(row, k) = base + ((k>>3)*16 + row)*16 + (k&7)*2
//   reads : lane l does ds_read_b128 at base + kt*1024 + l*16 (contiguous/wave)
//   writes: swapped-operand MFMA -> lane holds 4 consecutive k for batch lr
//           -> one ds_write_b64, even bank spread
// Y: 16x128k (4KB) | Z1/Z2: 16x256k (8KB; Z1 k>=128 = Static|0)
// X: 16x32k (1KB) | TS: 16x64 f32 (4KB)
// WH: 128out x 128k frag-major: addr(c,k)=((k>>3)*128+c)*16+(k&7)*2 (32KB)
#define LDS_Y   0
#define LDS_Z1  4096
#define LDS_Z2  12288
#define LDS_X   20480
#define LDS_TS  21504
#define LDS_WH  25600
#define LDS_TOT 58368

// branch-free fast activations (v_exp + v_rcp)
__device__ __forceinline__ float tanh_fast(float x) {
  return 2.0f * __builtin_amdgcn_rcpf(1.0f + __expf(-2.0f * x)) - 1.0f;
}
__device__ __forceinline__ float siluf(float x) {
  return x * __builtin_amdgcn_rcpf(1.0f + __expf(-x));
}

__global__ __launch_bounds__(512, 2)
void ode_rnn_kernel(const float* __restrict__ ts, const float* __restrict__ Xg,
                    const float* __restrict__ Sg,
                    const float* __restrict__ w0g, const float* __restrict__ b0g,
                    const float* __restrict__ w1g, const float* __restrict__ b1g,
                    const float* __restrict__ w2g, const float* __restrict__ b2g,
                    const float* __restrict__ scaleg,
                    const float* __restrict__ whg, const float* __restrict__ wxg,
                    const float* __restrict__ bxg,
                    const float* __restrict__ injwg, const float* __restrict__ injbg,
                    const float* __restrict__ ow0g, const float* __restrict__ ob0g,
                    const float* __restrict__ ow1g, const float* __restrict__ ob1g,
                    const float* __restrict__ ow2g, const float* __restrict__ ob2g,
                    float* __restrict__ outg) {
  const int t  = threadIdx.x;
  const int w  = t >> 6;       // wave 0..7
  const int l  = t & 63;       // lane
  const int lr = l & 15;       // batch row owned by this lane
  const int lg = l >> 4;       // 0..3
  const int rb = blockIdx.x * 16;
  const int c1 = w * 32;       // out-chan base, 256-wide stages
  const int c3 = w * 16;       // out-chan base, 128-wide stages

  __shared__ __align__(16) unsigned char lds[LDS_TOT];

  const int ard  = l * 16;                                   // frag read base (+kt*1024)
  const int whrd = LDS_WH + lg * 2048 + w * 256 + lr * 16;   // WH A-frag base (+kt*8192)
  const int awb  = (lg >> 1) * 256 + lr * 16 + (lg & 1) * 8; // b64 write base

  // ---------------- one-time staging into LDS ----------------
  for (int e = t; e < 16 * 64; e += 512) {
    *(float*)(lds + LDS_TS + e * 4) = ts[(size_t)(rb + (e >> 6)) * 64 + (e & 63)];
  }
  for (int e = t; e < 128 * 128; e += 512) {
    int c = e >> 7, kk = e & 127;
    *(f16*)(lds + LDS_WH + ((kk >> 3) * 128 + c) * 16 + (kk & 7) * 2) = (f16)whg[e];
  }
  {
    int r = t >> 5, d = t & 31;
    *(f16*)(lds + LDS_X + (d >> 3) * 256 + r * 16 + (d & 7) * 2) =
        (f16)Xg[(size_t)(rb + r) * 2048 + d];
  }
  if (t < 256) {
    int r = t >> 4, c = t & 15;
    *(f16*)(lds + LDS_Z1 + 4096 + (c >> 3) * 256 + r * 16 + (c & 7) * 2) =
        (f16)Sg[(size_t)(rb + r) * 16 + c];
    *(f16*)(lds + LDS_Z1 + 4608 + (c >> 3) * 256 + r * 16 + (c & 7) * 2) = (f16)0.0f;
  }

  // ---------------- per-channel constants (lane holds chans base+lg*4+r) ----------------
  f32x4 b0q[2], b1q[2];
  float w0c0[2][4];
  #pragma unroll
  for (int nt = 0; nt < 2; ++nt) {
    b0q[nt] = *(const f32x4*)(b0g + c1 + nt * 16 + lg * 4);
    b1q[nt] = *(const f32x4*)(b1g + c1 + nt * 16 + lg * 4);
    #pragma unroll
    for (int r = 0; r < 4; ++r)
      w0c0[nt][r] = w0g[(size_t)(c1 + nt * 16 + lg * 4 + r) * 129];
  }
  const f32x4 b2q = *(const f32x4*)(b2g + c3 + lg * 4);
  const f32x4 bxq = *(const f32x4*)(bxg + c3 + lg * 4);
  const float scalev = scaleg[0];

  // ---------------- register-resident weight fragments (f16, A-operand) ----------------
  auto ldfrag = [](const float* p) {
    f16x8 v;
    #pragma unroll
    for (int j = 0; j < 8; ++j) v[j] = (f16)p[j];
    return v;
  };

  f16x8 W0f[4][2];
  #pragma unroll
  for (int kt = 0; kt < 4; ++kt)
    #pragma unroll
    for (int nt = 0; nt < 2; ++nt)
      W0f[kt][nt] = ldfrag(w0g + (size_t)(c1 + nt * 16 + lr) * 129 + 1 + kt * 32 + lg * 8);

  f16x8 W1f[8][2];
  #pragma unroll
  for (int kt = 0; kt < 8; ++kt)
    #pragma unroll
    for (int nt = 0; nt < 2; ++nt)
      W1f[kt][nt] = ldfrag(w1g + (size_t)(c1 + nt * 16 + lr) * 256 + kt * 32 + lg * 8);

  f16x8 W2f[8];
  #pragma unroll
  for (int kt = 0; kt < 8; ++kt)
    W2f[kt] = ldfrag(w2g + (size_t)(c3 + lr) * 256 + kt * 32 + lg * 8);

  f16x8 WXf = ldfrag(wxg + (size_t)(c3 + lr) * 32 + lg * 8);

  __syncthreads();  // staging complete

  // ---------------- state ----------------
  float y[4];        // h[batch=lr][chan=c3+lg*4+r], fp32
  float tpv, dvv;

  auto writeY = [&](const float* yv) {
    f16x4 p;
    #pragma unroll
    for (int r = 0; r < 4; ++r) p[r] = (f16)yv[r];
    *(f16x4*)(lds + LDS_Y + w * 512 + awb) = p;
  };

  // ---------------- init: h0 = tanh(X0 @ wx.T + bx), then inj ----------------
  {
    f16x8 xa = *(const f16x8*)(lds + LDS_X + ard);
    f32x4 acc = {};
    acc = MFMA16(WXf, xa, acc);
    f16x4 p;
    #pragma unroll
    for (int r = 0; r < 4; ++r) p[r] = (f16)tanh_fast(acc[r] + bxq[r]);
    *(f16x4*)(lds + LDS_Z1 + w * 512 + awb) = p;   // h0 -> Z1 k=0..127
  }
  __syncthreads();
  {
    f16x8 af[5];
    #pragma unroll
    for (int kt = 0; kt < 5; ++kt) af[kt] = *(const f16x8*)(lds + LDS_Z1 + ard + kt * 1024);
    f32x4 acc = {};
    #pragma unroll
    for (int kt = 0; kt < 5; ++kt) {
      f16x8 bf;
      #pragma unroll
      for (int j = 0; j < 8; ++j) {
        int k = kt * 32 + lg * 8 + j;
        bf[j] = (k < 144) ? (f16)injwg[(size_t)(c3 + lr) * 144 + k] : (f16)0.0f;
      }
      acc = MFMA16(bf, af[kt], acc);
    }
    const f32x4 ibq = *(const f32x4*)(injbg + c3 + lg * 4);
    #pragma unroll
    for (int r = 0; r < 4; ++r) y[r] = tanh_fast(acc[r] + ibq[r]);
  }
  writeY(y);
  __syncthreads();

  // ---------------- f(t,y): 3 MFMA stages (4 interleaved acc chains each) ----------------
  auto feval = [&](float sc, float* ko) {
    f16x8 af[8];
    // stage1: K=128 from Y, 256 chans, + t*w0[:,0] + b0, silu -> Z1
    #pragma unroll
    for (int kt = 0; kt < 4; ++kt) af[kt] = *(const f16x8*)(lds + LDS_Y + ard + kt * 1024);
    f32x4 a1[2] = {}, a1b[2] = {};
    __builtin_amdgcn_s_setprio(1);
    #pragma unroll
    for (int kt = 0; kt < 2; ++kt)
      #pragma unroll
      for (int nt = 0; nt < 2; ++nt) {
        a1[nt]  = MFMA16(W0f[kt][nt],     af[kt],     a1[nt]);
        a1b[nt] = MFMA16(W0f[kt + 2][nt], af[kt + 2], a1b[nt]);
      }
    __builtin_amdgcn_s_setprio(0);
    const float tr = tpv + sc * dvv;
    #pragma unroll
    for (int nt = 0; nt < 2; ++nt) {
      f16x4 p;
      #pragma unroll
      for (int r = 0; r < 4; ++r)
        p[r] = (f16)siluf(a1[nt][r] + a1b[nt][r] + tr * w0c0[nt][r] + b0q[nt][r]);
      *(f16x4*)(lds + LDS_Z1 + w * 1024 + nt * 512 + awb) = p;
    }
    __syncthreads();
    // stage2: K=256 from Z1, 256 chans, +b1, silu -> Z2
    #pragma unroll
    for (int kt = 0; kt < 8; ++kt) af[kt] = *(const f16x8*)(lds + LDS_Z1 + ard + kt * 1024);
    f32x4 a2[2] = {}, a2b[2] = {};
    __builtin_amdgcn_s_setprio(1);
    #pragma unroll
    for (int kt = 0; kt < 4; ++kt)
      #pragma unroll
      for (int nt = 0; nt < 2; ++nt) {
        a2[nt]  = MFMA16(W1f[kt][nt],     af[kt],     a2[nt]);
        a2b[nt] = MFMA16(W1f[kt + 4][nt], af[kt + 4], a2b[nt]);
      }
    __builtin_amdgcn_s_setprio(0);
    #pragma unroll
    for (int nt = 0; nt < 2; ++nt) {
      f16x4 p;
      #pragma unroll
      for (int r = 0; r < 4; ++r)
        p[r] = (f16)siluf(a2[nt][r] + a2b[nt][r] + b1q[nt][r]);
      *(f16x4*)(lds + LDS_Z2 + w * 1024 + nt * 512 + awb) = p;
    }
    __syncthreads();
    // stage3: K=256 from Z2, 128 chans, scale*tanh(+b2) -> k (registers, 4 chains)
    #pragma unroll
    for (int kt = 0; kt < 8; ++kt) af[kt] = *(const f16x8*)(lds + LDS_Z2 + ard + kt * 1024);
    f32x4 a3 = {}, a3b = {}, a3c = {}, a3d = {};
    __builtin_amdgcn_s_setprio(1);
    #pragma unroll
    for (int kt = 0; kt < 2; ++kt) {
      a3  = MFMA16(W2f[kt],     af[kt],     a3);
      a3b = MFMA16(W2f[kt + 2], af[kt + 2], a3b);
      a3c = MFMA16(W2f[kt + 4], af[kt + 4], a3c);
      a3d = MFMA16(W2f[kt + 6], af[kt + 6], a3d);
    }
    __builtin_amdgcn_s_setprio(0);
    #pragma unroll
    for (int r = 0; r < 4; ++r)
      ko[r] = scalev * tanh_fast(((a3[r] + a3b[r]) + (a3c[r] + a3d[r])) + b2q[r]);
  };

  // ---------------- main time loop ----------------
  #pragma unroll 1
  for (int n = 0; n < 63; ++n) {
    {
      float tp = *(const float*)(lds + LDS_TS + (lr * 64 + n) * 4);
      float tn = *(const float*)(lds + LDS_TS + (lr * 64 + n + 1) * 4);
      tpv = tp;
      dvv = (tn - tp) * 0.5f;
    }
    // stage x = X[:, n+1] for this step's RNN (consumed after many barriers)
    {
      int r = t >> 5, d = t & 31;
      *(f16*)(lds + LDS_X + (d >> 3) * 256 + r * 16 + (d & 7) * 2) =
          (f16)Xg[(size_t)(rb + r) * 2048 + (size_t)(n + 1) * 32 + d];
    }

    #pragma unroll 1
    for (int s = 0; s < 2; ++s) {
      float k1v[4], k2v[4], k3v[4], k4v[4], k5v[4], k6v[4], yt[4];
      float sf = (float)s;
      feval(sf, k1v);
      #pragma unroll
      for (int i = 0; i < 4; ++i) yt[i] = y[i] + dvv * (A21f * k1v[i]);
      writeY(yt); __syncthreads();
      feval(sf + C2f, k2v);
      #pragma unroll
      for (int i = 0; i < 4; ++i) yt[i] = y[i] + dvv * (A31f * k1v[i] + A32f * k2v[i]);
      writeY(yt); __syncthreads();
      feval(sf + C3f, k3v);
      #pragma unroll
      for (int i = 0; i < 4; ++i) yt[i] = y[i] + dvv * (A41f * k1v[i] + A42f * k2v[i] + A43f * k3v[i]);
      writeY(yt); __syncthreads();
      feval(sf + C4f, k4v);
      #pragma unroll
      for (int i = 0; i < 4; ++i) yt[i] = y[i] + dvv * (A51f * k1v[i] + A52f * k2v[i] + A53f * k3v[i] + A54f * k4v[i]);
      writeY(yt); __syncthreads();
      feval(sf + C5f, k5v);
      #pragma unroll
      for (int i = 0; i < 4; ++i) yt[i] = y[i] + dvv * (A61f * k1v[i] + A62f * k2v[i] + A63f * k3v[i] + A64f * k4v[i] + A65f * k5v[i]);
      writeY(yt); __syncthreads();
      feval(sf + C6f, k6v);
      #pragma unroll
      for (int i = 0; i < 4; ++i)
        y[i] += dvv * (B1f * k1v[i] + B2f * k2v[i] + B3f * k3v[i] + B4f * k4v[i] + B5f * k5v[i] + B6f * k6v[i]);
      writeY(y); __syncthreads();
    }

    // RNN: h = tanh(hp@wh.T + x@wx.T + bx); wh A-frags from LDS, wx from regs
    {
      f16x8 ha[4];
      #pragma unroll
      for (int kt = 0; kt < 4; ++kt) ha[kt] = *(const f16x8*)(lds + LDS_Y + ard + kt * 1024);
      f16x8 xa = *(const f16x8*)(lds + LDS_X + ard);
      f32x4 acc = {}, accb = {};
      __builtin_amdgcn_s_setprio(1);
      #pragma unroll
      for (int kt = 0; kt < 2; ++kt) {
        f16x8 bf  = *(const f16x8*)(lds + whrd + kt * 8192);
        f16x8 bf2 = *(const f16x8*)(lds + whrd + (kt + 2) * 8192);
        acc  = MFMA16(bf,  ha[kt],     acc);
        accb = MFMA16(bf2, ha[kt + 2], accb);
      }
      acc = MFMA16(WXf, xa, acc);
      __builtin_amdgcn_s_setprio(0);
      #pragma unroll
      for (int r = 0; r < 4; ++r) y[r] = tanh_fast(acc[r] + accb[r] + bxq[r]);
      writeY(y);
      __syncthreads();
    }
  }

  // ---------------- output head ----------------
  auto ldfrag2 = [](const float* p) {
    f16x8 v;
    #pragma unroll
    for (int j = 0; j < 8; ++j) v[j] = (f16)p[j];
    return v;
  };
  // H1: z = tanh(hN @ out_w0.T + out_b0)   K=128 -> 256 chans
  {
    f16x8 ha[4];
    #pragma unroll
    for (int kt = 0; kt < 4; ++kt) ha[kt] = *(const f16x8*)(lds + LDS_Y + ard + kt * 1024);
    f32x4 acc[2] = {};
    #pragma unroll
    for (int kt = 0; kt < 4; ++kt)
      #pragma unroll
      for (int nt = 0; nt < 2; ++nt) {
        f16x8 bf = ldfrag2(ow0g + (size_t)(c1 + nt * 16 + lr) * 128 + kt * 32 + lg * 8);
        acc[nt] = MFMA16(bf, ha[kt], acc[nt]);
      }
    #pragma unroll
    for (int nt = 0; nt < 2; ++nt) {
      const f32x4 bb = *(const f32x4*)(ob0g + c1 + nt * 16 + lg * 4);
      f16x4 p;
      #pragma unroll
      for (int r = 0; r < 4; ++r) p[r] = (f16)tanh_fast(acc[nt][r] + bb[r]);
      *(f16x4*)(lds + LDS_Z1 + w * 1024 + nt * 512 + awb) = p;
    }
  }
  __syncthreads();
  // H2: z = tanh(z @ out_w1.T + out_b1)   K=256 -> 256 chans
  {
    f16x8 za[8];
    #pragma unroll
    for (int kt = 0; kt < 8; ++kt) za[kt] = *(const f16x8*)(lds + LDS_Z1 + ard + kt * 1024);
    f32x4 acc[2] = {};
    #pragma unroll
    for (int kt = 0; kt < 8; ++kt)
      #pragma unroll
      for (int nt = 0; nt < 2; ++nt) {
        f16x8 bf = ldfrag2(ow1g + (size_t)(c1 + nt * 16 + lr) * 256 + kt * 32 + lg * 8);
        acc[nt] = MFMA16(bf, za[kt], acc[nt]);
      }
    #pragma unroll
    for (int nt = 0; nt < 2; ++nt) {
      const f32x4 bb = *(const f32x4*)(ob1g + c1 + nt * 16 + lg * 4);
      f16x4 p;
      #pragma unroll
      for (int r = 0; r < 4; ++r) p[r] = (f16)tanh_fast(acc[nt][r] + bb[r]);
      *(f16x4*)(lds + LDS_Z2 + w * 1024 + nt * 512 + awb) = p;
    }
  }
  __syncthreads();
  // H3: out = z @ out_w2.T + out_b2   K=256 -> 16 chans (wave 0 only)
  if (w == 0) {
    f16x8 za[8];
    #pragma unroll
    for (int kt = 0; kt < 8; ++kt) za[kt] = *(const f16x8*)(lds + LDS_Z2 + ard + kt * 1024);
    f32x4 acc = {};
    #pragma unroll
    for (int kt = 0; kt < 8; ++kt) {
      f16x8 bf = ldfrag2(ow2g + (size_t)lr * 256 + kt * 32 + lg * 8);
      acc = MFMA16(bf, za[kt], acc);
    }
    const f32x4 bb = *(const f32x4*)(ob2g + lg * 4);
    f32x4 vout;
    #pragma unroll
    for (int r = 0; r < 4; ++r) vout[r] = acc[r] + bb[r];
    *(f32x4*)(outg + (size_t)(rb + lr) * 16 + lg * 4) = vout;
  }
}

extern "C" void kernel_launch(void* const* d_in, const int* in_sizes, int n_in,
                              void* d_out, int out_size, void* d_ws, size_t ws_size,
                              hipStream_t stream) {
  (void)in_sizes; (void)n_in; (void)d_ws; (void)ws_size; (void)out_size;
  ode_rnn_kernel<<<dim3(8), dim3(512), 0, stream>>>(
      (const float*)d_in[0],  (const float*)d_in[1],  (const float*)d_in[2],
      (const float*)d_in[3],  (const float*)d_in[4],  (const float*)d_in[5],
      (const float*)d_in[6],  (const float*)d_in[7],  (const float*)d_in[8],
      (const float*)d_in[9],  (const float*)d_in[10], (const float*)d_in[11],
      (const float*)d_in[12], (const float*)d_in[13], (const float*)d_in[14],
      (const float*)d_in[15], (const float*)d_in[16], (const float*)d_in[17],
      (const float*)d_in[18], (const float*)d_in[19], (const float*)d_in[20],
      (float*)d_out);
}